// Round 1
// baseline (743.070 us; speedup 1.0000x reference)
//
#include <hip/hip_runtime.h>
#include <stdint.h>

// ProbSparse attention (Informer) for B=4, L=2048, H=8, D=64, factor=5 -> U_part=u=40.
// Output = broadcast mean(V over L) except top-40 query rows per (b,h) get full attention.
// Row selection requires bit-exact reproduction of jax.random.randint(key(42),(2048,40),0,2048).
//
// PARTITIONABLE=1 : jax_threefry_partitionable=True semantics (JAX >= 0.4.36 default)
// PARTITIONABLE=0 : legacy threefry split / random_bits
#define PARTITIONABLE 1

static constexpr int Bc = 4, Lc = 2048, Hc = 8, Dc = 64, NSc = 40, NUc = 40;

__device__ __forceinline__ uint32_t rotl32(uint32_t x, int r) {
    return (x << r) | (x >> (32 - r));
}

// Threefry-2x32, 20 rounds, exactly as jax._src.prng.threefry2x32
__device__ __forceinline__ void tf2x32(uint32_t k0, uint32_t k1, uint32_t x0, uint32_t x1,
                                       uint32_t& o0, uint32_t& o1) {
    uint32_t ks0 = k0, ks1 = k1, ks2 = k0 ^ k1 ^ 0x1BD11BDAu;
    uint32_t ks[3] = {ks0, ks1, ks2};
    const int R0[4] = {13, 15, 26, 6};
    const int R1[4] = {17, 29, 16, 24};
    x0 += ks[0];
    x1 += ks[1];
#pragma unroll
    for (int i = 0; i < 5; ++i) {
        const int* R = (i & 1) ? R1 : R0;
#pragma unroll
        for (int j = 0; j < 4; ++j) {
            x0 += x1;
            x1 = rotl32(x1, R[j]);
            x1 ^= x0;
        }
        x0 += ks[(i + 1) % 3];
        x1 += ks[(i + 2) % 3] + (uint32_t)(i + 1);
    }
    o0 = x0;
    o1 = x1;
}

// index_sample[j], j in [0, 2048*40). Base key for jax.random.key(42) is (hi=0, lo=42).
// randint span=2048 is a power of two -> multiplier==0 -> index = lower_bits % 2048,
// where lower_bits come from the SECOND key of split(key).
__global__ void k_index(int* __restrict__ idx) {
    int j = blockIdx.x * blockDim.x + threadIdx.x;
    if (j >= Lc * NSc) return;
    uint32_t a, b;
#if PARTITIONABLE
    // fold-like split: key2 = full output pair of threefry(base, (0,1))
    uint32_t k2a, k2b;
    tf2x32(0u, 42u, 0u, 1u, k2a, k2b);
    // partitionable 32-bit random bits: element j -> xor-fold of threefry(key2, (0, j))
    tf2x32(k2a, k2b, 0u, (uint32_t)j, a, b);
    idx[j] = (int)((a ^ b) & 2047u);
#else
    // original split: counts=[0,1,2,3] -> pairs (0,2),(1,3); k2 = (out1 of (0,2), out1 of (1,3))
    uint32_t A0, B0, A1, B1;
    tf2x32(0u, 42u, 0u, 2u, A0, B0);
    tf2x32(0u, 42u, 1u, 3u, A1, B1);
    // original random_bits for 81920 elems: halves [0..40959] and [40960..81919]
    uint32_t bits;
    if (j < 40960) {
        tf2x32(B0, B1, (uint32_t)j, (uint32_t)(j + 40960), a, b);
        bits = a;
    } else {
        tf2x32(B0, B1, (uint32_t)(j - 40960), (uint32_t)j, a, b);
        bits = b;
    }
    idx[j] = (int)(bits & 2047u);
#endif
}

// M[b,h,q] = max_s(Q.Ks) - sum_s(Q.Ks)/2048 over the 40 sampled keys.
// One wave per (b,h,q) row; lane d handles dim d; shuffle-reduce each dot.
__global__ void k_M(const float* __restrict__ Q, const float* __restrict__ K,
                    const int* __restrict__ idx, float* __restrict__ M) {
    int lane = threadIdx.x & 63;
    int w = threadIdx.x >> 6;
    int row = blockIdx.x * 4 + w;  // row = (b*8+h)*2048 + q
    int q = row & 2047;
    int h = (row >> 11) & 7;
    int b = row >> 14;
    float qv = Q[(((size_t)(b * Lc + q)) * Hc + h) * Dc + lane];
    float mx = -INFINITY, sm = 0.f;
    for (int s = 0; s < NSc; ++s) {
        int kk = idx[q * NSc + s];
        float pv = qv * K[(((size_t)(b * Lc + kk)) * Hc + h) * Dc + lane];
#pragma unroll
        for (int m = 32; m; m >>= 1) pv += __shfl_xor(pv, m, 64);
        mx = fmaxf(mx, pv);
        sm += pv;
    }
    if (lane == 0) M[row] = mx - sm * (1.0f / 2048.0f);
}

// Stable top-40 per (b,h): iterative argmax with ties -> smaller index (matches lax.top_k).
__global__ void k_topk(const float* __restrict__ M, int* __restrict__ top) {
    __shared__ float vals[2048];
    __shared__ float rv[256];
    __shared__ int ri[256];
    int bh = blockIdx.x;  // b*8+h
    int t = threadIdx.x;
    for (int k = t; k < Lc; k += 256) vals[k] = M[bh * Lc + k];
    __syncthreads();
    for (int it = 0; it < NUc; ++it) {
        float bv = -INFINITY;
        int bi = 0x7fffffff;
        for (int k = t; k < Lc; k += 256) {
            float v = vals[k];
            if (v > bv || (v == bv && k < bi)) { bv = v; bi = k; }
        }
        rv[t] = bv;
        ri[t] = bi;
        __syncthreads();
        for (int s = 128; s; s >>= 1) {
            if (t < s) {
                float ov = rv[t + s];
                int oi = ri[t + s];
                if (ov > rv[t] || (ov == rv[t] && oi < ri[t])) { rv[t] = ov; ri[t] = oi; }
            }
            __syncthreads();
        }
        if (t == 0) {
            top[bh * NUc + it] = ri[0];
            vals[ri[0]] = -INFINITY;
        }
        __syncthreads();
    }
}

// vmean[b,h,d] = mean over l of V[b,l,h,d]
__global__ void k_vmean(const float* __restrict__ V, float* __restrict__ vm) {
    __shared__ float r[256];
    int bh = blockIdx.x;
    int b = bh >> 3, h = bh & 7;
    int t = threadIdx.x;
    int d = t & 63, c = t >> 6;
    float s = 0.f;
    for (int l = c; l < Lc; l += 4) s += V[(((size_t)(b * Lc + l)) * Hc + h) * Dc + d];
    r[t] = s;
    __syncthreads();
    if (c == 0) vm[bh * Dc + d] = (r[d] + r[64 + d] + r[128 + d] + r[192 + d]) * (1.0f / 2048.0f);
}

// out[b,l,h,d] = vmean[b,h,d] for all l (float4-vectorized, coalesced)
__global__ void k_fill(float* __restrict__ out, const float* __restrict__ vm) {
    int o4 = blockIdx.x * blockDim.x + threadIdx.x;  // over 1M float4
    if (o4 >= Bc * Lc * Hc * (Dc / 4)) return;
    int dq = o4 & 15;
    int h = (o4 >> 4) & 7;
    int bl = o4 >> 7;  // b*2048 + l
    int b = bl >> 11;
    float4 v = reinterpret_cast<const float4*>(vm)[(b * 8 + h) * 16 + dq];
    reinterpret_cast<float4*>(out)[o4] = v;
}

// Full attention for the selected rows: one block per (b,h,u).
__global__ void k_attn(const float* __restrict__ Q, const float* __restrict__ K,
                       const float* __restrict__ V, const int* __restrict__ top,
                       float* __restrict__ out) {
    __shared__ float sc[2048];
    __shared__ float qrow[64];
    __shared__ float rv[256];
    int bhu = blockIdx.x;  // (b*8+h)*40 + u
    int u = bhu % NUc;
    int bh = bhu / NUc;
    int b = bh >> 3, h = bh & 7;
    int t = threadIdx.x;
    int q = top[bh * NUc + u];
    if (t < 64) qrow[t] = Q[(((size_t)(b * Lc + q)) * Hc + h) * Dc + t];
    __syncthreads();
    // scores
    float lmax = -INFINITY;
    for (int k = t; k < Lc; k += 256) {
        const float4* Kr = reinterpret_cast<const float4*>(&K[(((size_t)(b * Lc + k)) * Hc + h) * Dc]);
        const float4* Qr = reinterpret_cast<const float4*>(qrow);
        float dot = 0.f;
#pragma unroll
        for (int i = 0; i < 16; ++i) {
            float4 kv = Kr[i];
            float4 qv = Qr[i];
            dot += qv.x * kv.x + qv.y * kv.y + qv.z * kv.z + qv.w * kv.w;
        }
        dot *= 0.125f;  // 1/sqrt(64)
        sc[k] = dot;
        lmax = fmaxf(lmax, dot);
    }
    rv[t] = lmax;
    __syncthreads();
    for (int s = 128; s; s >>= 1) {
        if (t < s) rv[t] = fmaxf(rv[t], rv[t + s]);
        __syncthreads();
    }
    float mx = rv[0];
    __syncthreads();
    // exp + sum
    float lsum = 0.f;
    for (int k = t; k < Lc; k += 256) {
        float e = expf(sc[k] - mx);
        sc[k] = e;
        lsum += e;
    }
    rv[t] = lsum;
    __syncthreads();
    for (int s = 128; s; s >>= 1) {
        if (t < s) rv[t] += rv[t + s];
        __syncthreads();
    }
    float inv = 1.0f / rv[0];
    __syncthreads();
    // PV: thread (d, c) accumulates over k ≡ c (mod 4); coalesced over d
    int d = t & 63, c = t >> 6;
    float acc = 0.f;
    for (int k = c; k < Lc; k += 4) acc += sc[k] * V[(((size_t)(b * Lc + k)) * Hc + h) * Dc + d];
    rv[t] = acc;
    __syncthreads();
    if (c == 0)
        out[(((size_t)(b * Lc + q)) * Hc + h) * Dc + d] =
            (rv[d] + rv[64 + d] + rv[128 + d] + rv[192 + d]) * inv;
}

extern "C" void kernel_launch(void* const* d_in, const int* in_sizes, int n_in,
                              void* d_out, int out_size, void* d_ws, size_t ws_size,
                              hipStream_t stream) {
    (void)in_sizes; (void)n_in; (void)out_size; (void)ws_size;
    const float* Q = (const float*)d_in[0];
    const float* K = (const float*)d_in[1];
    const float* V = (const float*)d_in[2];
    float* out = (float*)d_out;

    // Scratch: idx (320KB) and M (256KB) live in d_out (fully overwritten by k_fill later);
    // top (5KB) and vmean (8KB) must survive past k_fill -> keep in d_ws.
    int* idx = (int*)d_out;
    float* M = (float*)((char*)d_out + 327680);
    int* top = (int*)d_ws;
    float* vm = (float*)((char*)d_ws + 5120);

    hipLaunchKernelGGL(k_index, dim3(320), dim3(256), 0, stream, idx);
    hipLaunchKernelGGL(k_M, dim3((Bc * Hc * Lc) / 4), dim3(256), 0, stream, Q, K, idx, M);
    hipLaunchKernelGGL(k_topk, dim3(Bc * Hc), dim3(256), 0, stream, M, top);
    hipLaunchKernelGGL(k_vmean, dim3(Bc * Hc), dim3(256), 0, stream, V, vm);
    hipLaunchKernelGGL(k_fill, dim3((Bc * Lc * Hc * (Dc / 4)) / 256), dim3(256), 0, stream, out, vm);
    hipLaunchKernelGGL(k_attn, dim3(Bc * Hc * NUc), dim3(256), 0, stream, Q, K, V, top, out);
}

// Round 3
// 282.579 us; speedup vs baseline: 2.6296x; 2.6296x over previous
//
#include <hip/hip_runtime.h>
#include <stdint.h>

// ProbSparse attention (Informer): B=4, L=2048, H=8, D=64, factor=5 -> U_part=u=40.
// out = broadcast mean(V) except top-40 rows per (b,h) get softmax(Q K^T/8) V.
// Row selection is bit-exact jax.random.randint(key(42),(2048,40),0,2048)
// under jax_threefry_partitionable=True (verified passing in round 1).
//
// Round 2 bug: k_attn_comb loaded 320 stat pairs under `if (t < 320)` with only
// 256 threads -> chunks 6(partial)/7 stats uninitialized. Fixed with strided loop.

static constexpr int Bc = 4, Lc = 2048, Hc = 8, Dc = 64, NUc = 40;
static constexpr int NCH = 8, CHK = 256;  // key chunks for attention

struct TF2 { uint32_t a, b; };

__host__ __device__ constexpr uint32_t rotl32c(uint32_t x, int r) {
    return (x << r) | (x >> (32 - r));
}

// Threefry-2x32, 20 rounds (jax._src.prng.threefry2x32), constexpr-foldable.
__host__ __device__ constexpr TF2 tf2x32c(uint32_t k0, uint32_t k1, uint32_t x0, uint32_t x1) {
    uint32_t ks[3] = {k0, k1, k0 ^ k1 ^ 0x1BD11BDAu};
    const int R0[4] = {13, 15, 26, 6};
    const int R1[4] = {17, 29, 16, 24};
    x0 += ks[0];
    x1 += ks[1];
    for (int i = 0; i < 5; ++i) {
        const int* R = (i & 1) ? R1 : R0;
        for (int j = 0; j < 4; ++j) {
            x0 += x1;
            x1 = rotl32c(x1, R[j]);
            x1 ^= x0;
        }
        x0 += ks[(i + 1) % 3];
        x1 += ks[(i + 2) % 3] + (uint32_t)(i + 1);
    }
    return TF2{x0, x1};
}

// ---------------- k_M: sampled sparsity measure, fused index-gen, 8-wide ILP ----
// wave per q-row; lane = d. M[b,h,q] = max_s(QKs) - sum_s(QKs)/2048.
__global__ __launch_bounds__(256) void k_M(const float* __restrict__ Q,
                                           const float* __restrict__ K,
                                           float* __restrict__ M) {
    constexpr TF2 K2 = tf2x32c(0u, 42u, 0u, 1u);  // second key of split(key(42))
    int lane = threadIdx.x & 63;
    int w = threadIdx.x >> 6;
    int row = blockIdx.x * 4 + w;  // (b*8+h)*2048 + q
    int q = row & 2047;
    int bh = row >> 11;
    int b = bh >> 3, h = bh & 7;
    // lane s (<40) computes index_sample[q][s]
    TF2 r = tf2x32c(K2.a, K2.b, 0u, (uint32_t)(q * 40 + lane));
    int myidx = (int)((r.a ^ r.b) & 2047u);

    float qv = Q[(((size_t)(b * Lc + q)) * Hc + h) * Dc + lane];
    const float* Kbh = K + ((size_t)b * Lc * Hc + h) * Dc;  // + l*512 + lane
    float mx = -INFINITY, sm = 0.f;
#pragma unroll
    for (int s0 = 0; s0 < 40; s0 += 8) {
        float pv[8];
#pragma unroll
        for (int j = 0; j < 8; ++j) {
            int kk = __shfl(myidx, s0 + j, 64);
            pv[j] = qv * Kbh[(size_t)kk * 512 + lane];
        }
#pragma unroll
        for (int m = 32; m; m >>= 1)
#pragma unroll
            for (int j = 0; j < 8; ++j) pv[j] += __shfl_xor(pv[j], m, 64);
#pragma unroll
        for (int j = 0; j < 8; ++j) {
            mx = fmaxf(mx, pv[j]);
            sm += pv[j];
        }
    }
    if (lane == 0) M[row] = mx - sm * (1.0f / 2048.0f);
}

// ---------------- k_topk: register-resident iterative argmax (ties -> smaller idx) --
__global__ __launch_bounds__(256) void k_topk(const float* __restrict__ M, int* __restrict__ top) {
    __shared__ float wvs[4];
    __shared__ int wis[4];
    int bh = blockIdx.x;
    int t = threadIdx.x, lane = t & 63, w = t >> 6;
    float v[8];
#pragma unroll
    for (int i = 0; i < 8; ++i) v[i] = M[bh * Lc + i * 256 + t];
    float bv;
    int bi;
    auto recompute = [&]() {
        bv = v[0];
        bi = t;
#pragma unroll
        for (int i = 1; i < 8; ++i)
            if (v[i] > bv) { bv = v[i]; bi = i * 256 + t; }
    };
    recompute();
    for (int it = 0; it < NUc; ++it) {
        float cv = bv;
        int ci = bi;
#pragma unroll
        for (int m = 1; m < 64; m <<= 1) {
            float ov = __shfl_xor(cv, m, 64);
            int oi = __shfl_xor(ci, m, 64);
            if (ov > cv || (ov == cv && oi < ci)) { cv = ov; ci = oi; }
        }
        if (lane == 0) { wvs[w] = cv; wis[w] = ci; }
        __syncthreads();
        float gv = wvs[0];
        int gi = wis[0];
#pragma unroll
        for (int ww = 1; ww < 4; ++ww) {
            float ov = wvs[ww];
            int oi = wis[ww];
            if (ov > gv || (ov == gv && oi < gi)) { gv = ov; gi = oi; }
        }
        if (t == 0) top[bh * NUc + it] = gi;
        if ((gi & 255) == t) {  // owner removes and rescans its 8
            v[gi >> 8] = -INFINITY;
            recompute();
        }
        __syncthreads();
    }
}

// ---------------- V mean: partial over 256-row chunks, then reduce ---------------
__global__ __launch_bounds__(256) void k_vmean_part(const float* __restrict__ V,
                                                    float* __restrict__ vpart) {
    __shared__ float4 r[256];
    int blk = blockIdx.x;  // bh*8 + chunk
    int chunk = blk & 7, bh = blk >> 3;
    int b = bh >> 3, h = bh & 7;
    int t = threadIdx.x, dq = t & 15, c = t >> 4;  // c in 0..15
    const float4* V4 = reinterpret_cast<const float4*>(V);
    float4 s = make_float4(0.f, 0.f, 0.f, 0.f);
#pragma unroll
    for (int i = 0; i < 16; ++i) {
        int l = chunk * 256 + c + 16 * i;
        float4 p = V4[(size_t)((b * Lc + l) * Hc + h) * 16 + dq];
        s.x += p.x; s.y += p.y; s.z += p.z; s.w += p.w;
    }
    r[t] = s;
    __syncthreads();
    if (t < 16) {
        float4 a = r[t];
#pragma unroll
        for (int g = 1; g < 16; ++g) {
            float4 p = r[t + 16 * g];
            a.x += p.x; a.y += p.y; a.z += p.z; a.w += p.w;
        }
        reinterpret_cast<float4*>(vpart)[blk * 16 + t] = a;
    }
}

__global__ void k_vred(const float* __restrict__ vpart, float* __restrict__ vm) {
    int i = blockIdx.x * 256 + threadIdx.x;  // < 2048 : bh*64 + d
    int bh = i >> 6, d = i & 63;
    float s = 0.f;
#pragma unroll
    for (int c = 0; c < 8; ++c) s += vpart[(bh * 8 + c) * 64 + d];
    vm[i] = s * (1.0f / 2048.0f);
}

// ---------------- attention partials: block = (b,h,chunk of 256 keys) ------------
__global__ __launch_bounds__(256) void k_attn_part(const float* __restrict__ Q,
                                                   const float* __restrict__ K,
                                                   const float* __restrict__ V,
                                                   const int* __restrict__ top,
                                                   float* __restrict__ wsO,
                                                   float* __restrict__ wsm,
                                                   float* __restrict__ wsl) {
    __shared__ float Qs[40][64];        // 10 KB
    __shared__ float pT[4][64][44];     // 44 KB (wave, key-local, u + pad)
    __shared__ float mw[4][40], lw[4][40];
    __shared__ float Mgs[40], Lgs[40];
    __shared__ int tqs[40];
    int blk = blockIdx.x;  // bh*NCH + chunk
    int chunk = blk & (NCH - 1), bh = blk >> 3;
    int b = bh >> 3, h = bh & 7;
    int t = threadIdx.x, w = t >> 6, lane = t & 63;

    if (t < 40) tqs[t] = top[bh * NUc + t];
    __syncthreads();
    for (int i = t; i < 40 * 64; i += 256) {
        int u = i >> 6, d = i & 63;
        Qs[u][d] = Q[(((size_t)(b * Lc + tqs[u])) * Hc + h) * Dc + d];
    }
    __syncthreads();

    // scores: thread t owns key kg = chunk*256 + t; acc[u] = dot(Q[u], K[kg])
    int kg = chunk * CHK + t;
    const float4* Kr = reinterpret_cast<const float4*>(&K[(((size_t)(b * Lc + kg)) * Hc + h) * Dc]);
    float acc[40];
#pragma unroll
    for (int u = 0; u < 40; ++u) acc[u] = 0.f;
#pragma unroll
    for (int i = 0; i < 16; ++i) {
        float4 kv = Kr[i];
#pragma unroll
        for (int u = 0; u < 40; ++u) {
            float4 qv = *reinterpret_cast<const float4*>(&Qs[u][i * 4]);
            acc[u] += qv.x * kv.x + qv.y * kv.y + qv.z * kv.z + qv.w * kv.w;
        }
    }
    // transpose into wave-local LDS (scaled); same-wave, no barrier needed
#pragma unroll
    for (int u = 0; u < 40; ++u) pT[w][lane][u] = acc[u] * 0.125f;
    // wave-local softmax stats over this wave's 64 keys (lane u < 40)
    if (lane < 40) {
        float m = -INFINITY;
        for (int k = 0; k < 64; ++k) m = fmaxf(m, pT[w][k][lane]);
        float s = 0.f;
        for (int k = 0; k < 64; ++k) {
            float e = __expf(pT[w][k][lane] - m);
            pT[w][k][lane] = e;
            s += e;
        }
        mw[w][lane] = m;
        lw[w][lane] = s;
    }
    // PV over this wave's 64 keys: lane = d, acc[u] = sum_k p[u][k] * V[k][d]
#pragma unroll
    for (int u = 0; u < 40; ++u) acc[u] = 0.f;
    const float* Vbh = V + ((size_t)b * Lc * Hc + h) * Dc;
    for (int k = 0; k < 64; ++k) {
        int kk = chunk * CHK + w * 64 + k;
        float vv = Vbh[(size_t)kk * 512 + lane];
#pragma unroll
        for (int u0 = 0; u0 < 40; u0 += 4) {
            float4 p4 = *reinterpret_cast<const float4*>(&pT[w][k][u0]);
            acc[u0] += p4.x * vv;
            acc[u0 + 1] += p4.y * vv;
            acc[u0 + 2] += p4.z * vv;
            acc[u0 + 3] += p4.w * vv;
        }
    }
    __syncthreads();
    // combine 4 waves' stats -> chunk stats; lw becomes per-wave rescale factor
    if (t < 40) {
        float m = fmaxf(fmaxf(mw[0][t], mw[1][t]), fmaxf(mw[2][t], mw[3][t]));
        float L = 0.f;
#pragma unroll
        for (int ww = 0; ww < 4; ++ww) {
            float f = __expf(mw[ww][t] - m);
            L += lw[ww][t] * f;
            lw[ww][t] = f;
        }
        Mgs[t] = m;
        Lgs[t] = L;
    }
    __syncthreads();
    // scale own O by factor, stage into pT region (p no longer needed)
    float* Ow = &pT[w][0][0];
#pragma unroll
    for (int u = 0; u < 40; ++u) Ow[u * 64 + lane] = acc[u] * lw[w][u];
    __syncthreads();
    // sum across waves -> chunk partial (unnormalized, referenced to chunk max)
    const float* o0 = &pT[0][0][0];
    const float* o1 = &pT[1][0][0];
    const float* o2 = &pT[2][0][0];
    const float* o3 = &pT[3][0][0];
    for (int i = t; i < 40 * 64; i += 256)
        wsO[(size_t)blk * 2560 + i] = o0[i] + o1[i] + o2[i] + o3[i];
    if (t < 40) {
        wsm[blk * 40 + t] = Mgs[t];
        wsl[blk * 40 + t] = Lgs[t];
    }
}

// ---------------- combine 8 chunk-partials -> staged rows ------------------------
__global__ __launch_bounds__(256) void k_attn_comb(const float* __restrict__ wsO,
                                                   const float* __restrict__ wsm,
                                                   const float* __restrict__ wsl,
                                                   float* __restrict__ stage) {
    __shared__ float cm[8][40], cl[8][40], cf[8][40];
    int bh = blockIdx.x;
    int t = threadIdx.x;
    // FIX (round 2 bug): 320 pairs, 256 threads -> strided loop, not `if (t < 320)`.
    for (int i = t; i < 8 * 40; i += 256) {
        int c = i / 40, u = i % 40;
        cm[c][u] = wsm[(bh * 8 + c) * 40 + u];
        cl[c][u] = wsl[(bh * 8 + c) * 40 + u];
    }
    __syncthreads();
    if (t < 40) {
        float m = -INFINITY;
#pragma unroll
        for (int c = 0; c < 8; ++c) m = fmaxf(m, cm[c][t]);
        float L = 0.f;
#pragma unroll
        for (int c = 0; c < 8; ++c) {
            float f = __expf(cm[c][t] - m);
            L += cl[c][t] * f;
            cf[c][t] = f;
        }
        float inv = 1.0f / L;
#pragma unroll
        for (int c = 0; c < 8; ++c) cf[c][t] *= inv;
    }
    __syncthreads();
    for (int i = t; i < 2560; i += 256) {
        int u = i >> 6;
        float val = 0.f;
#pragma unroll
        for (int c = 0; c < 8; ++c) val += wsO[((size_t)(bh * 8 + c)) * 2560 + i] * cf[c][u];
        stage[(size_t)bh * 2560 + i] = val;
    }
}

// ---------------- fill with mean(V), then scatter attended rows ------------------
__global__ void k_fill(float* __restrict__ out, const float* __restrict__ vm) {
    int o4 = blockIdx.x * blockDim.x + threadIdx.x;  // over 1M float4
    if (o4 >= Bc * Lc * Hc * (Dc / 4)) return;
    int dq = o4 & 15;
    int h = (o4 >> 4) & 7;
    int bl = o4 >> 7;
    int b = bl >> 11;
    float4 v = reinterpret_cast<const float4*>(vm)[(b * 8 + h) * 16 + dq];
    reinterpret_cast<float4*>(out)[o4] = v;
}

__global__ void k_scatter(const float* __restrict__ stage, const int* __restrict__ top,
                          float* __restrict__ out) {
    int i = blockIdx.x * 256 + threadIdx.x;  // < 32*2560
    if (i >= 32 * 2560) return;
    int bh = i / 2560;
    int rem = i % 2560;
    int u = rem >> 6, d = rem & 63;
    int b = bh >> 3, h = bh & 7;
    int q = top[bh * NUc + u];
    out[(((size_t)(b * Lc + q)) * Hc + h) * Dc + d] = stage[i];
}

extern "C" void kernel_launch(void* const* d_in, const int* in_sizes, int n_in,
                              void* d_out, int out_size, void* d_ws, size_t ws_size,
                              hipStream_t stream) {
    (void)in_sizes; (void)n_in; (void)out_size; (void)ws_size;
    const float* Q = (const float*)d_in[0];
    const float* K = (const float*)d_in[1];
    const float* V = (const float*)d_in[2];
    float* out = (float*)d_out;

    // d_out-as-scratch (16 MB; all consumed before k_fill overwrites it):
    float* wsO = (float*)d_out;                           // 0 .. 2.62 MB
    float* wsm = (float*)((char*)d_out + 3145728);        // 40 KB
    float* wsl = (float*)((char*)d_out + 3276800);        // 40 KB
    float* M   = (float*)((char*)d_out + 4194304);        // 256 KB
    // d_ws (survives past k_fill): ~410 KB total
    int*   top   = (int*)d_ws;                            // 5 KB
    float* stage = (float*)((char*)d_ws + 8192);          // 320 KB
    float* vpart = (float*)((char*)d_ws + 335872);        // 64 KB
    float* vm    = (float*)((char*)d_ws + 401408);        // 8 KB

    hipLaunchKernelGGL(k_M, dim3((Bc * Hc * Lc) / 4), dim3(256), 0, stream, Q, K, M);
    hipLaunchKernelGGL(k_topk, dim3(Bc * Hc), dim3(256), 0, stream, M, top);
    hipLaunchKernelGGL(k_vmean_part, dim3(Bc * Hc * 8), dim3(256), 0, stream, V, vpart);
    hipLaunchKernelGGL(k_vred, dim3(8), dim3(256), 0, stream, vpart, vm);
    hipLaunchKernelGGL(k_attn_part, dim3(Bc * Hc * NCH), dim3(256), 0, stream, Q, K, V, top,
                       wsO, wsm, wsl);
    hipLaunchKernelGGL(k_attn_comb, dim3(Bc * Hc), dim3(256), 0, stream, wsO, wsm, wsl, stage);
    hipLaunchKernelGGL(k_fill, dim3(4096), dim3(256), 0, stream, out, vm);
    hipLaunchKernelGGL(k_scatter, dim3(320), dim3(256), 0, stream, stage, top, out);
}

// Round 4
// 257.557 us; speedup vs baseline: 2.8851x; 1.0972x over previous
//
#include <hip/hip_runtime.h>
#include <stdint.h>

// ProbSparse attention (Informer): B=4, L=2048, H=8, D=64, factor=5 -> U_part=u=40.
// out = broadcast mean(V) except top-40 rows per (b,h) get softmax(Q K^T/8) V.
// Row selection is bit-exact jax.random.randint(key(42),(2048,40),0,2048)
// under jax_threefry_partitionable=True (verified passing).
//
// R3 profile: k_M = 202/283 us, FETCH 73 MB @ 375 GB/s (= dur) -> L2-miss bound:
// each (b,h) K-panel (512 KB) was re-fetched by every XCD. R4 fix: XCD-affinity
// block remap (4 panels per XCD, 2 MB resident in 4 MB L2) + readlane instead of
// shfl for the wave-uniform sample index.

static constexpr int Bc = 4, Lc = 2048, Hc = 8, Dc = 64, NUc = 40;
static constexpr int NCH = 8, CHK = 256;  // key chunks for attention

struct TF2 { uint32_t a, b; };

__host__ __device__ constexpr uint32_t rotl32c(uint32_t x, int r) {
    return (x << r) | (x >> (32 - r));
}

// Threefry-2x32, 20 rounds (jax._src.prng.threefry2x32), constexpr-foldable.
__host__ __device__ constexpr TF2 tf2x32c(uint32_t k0, uint32_t k1, uint32_t x0, uint32_t x1) {
    uint32_t ks[3] = {k0, k1, k0 ^ k1 ^ 0x1BD11BDAu};
    const int R0[4] = {13, 15, 26, 6};
    const int R1[4] = {17, 29, 16, 24};
    x0 += ks[0];
    x1 += ks[1];
    for (int i = 0; i < 5; ++i) {
        const int* R = (i & 1) ? R1 : R0;
        for (int j = 0; j < 4; ++j) {
            x0 += x1;
            x1 = rotl32c(x1, R[j]);
            x1 ^= x0;
        }
        x0 += ks[(i + 1) % 3];
        x1 += ks[(i + 2) % 3] + (uint32_t)(i + 1);
    }
    return TF2{x0, x1};
}

// ---------------- k_M: sampled sparsity measure --------------------------------
// wave per q-row; lane = d. M[b,h,q] = max_s(QKs) - sum_s(QKs)/2048.
// Block remap: blk&7 selects XCD (dispatch round-robins consecutive blockIdx
// across XCDs), each XCD owns 4 consecutive (b,h) panels -> K gathers L2-hit.
__global__ __launch_bounds__(256) void k_M(const float* __restrict__ Q,
                                           const float* __restrict__ K,
                                           float* __restrict__ M) {
    constexpr TF2 K2 = tf2x32c(0u, 42u, 0u, 1u);  // second key of split(key(42))
    int lane = threadIdx.x & 63;
    int w = threadIdx.x >> 6;
    int blk = blockIdx.x;           // 16384 blocks
    int xcd = blk & 7;
    int local = blk >> 3;           // 0..2047 within XCD
    int bh = xcd * 4 + (local >> 9);   // 4 panels per XCD
    int q = (local & 511) * 4 + w;
    int b = bh >> 3, h = bh & 7;
    // lane s (<40) computes index_sample[q][s]
    TF2 r = tf2x32c(K2.a, K2.b, 0u, (uint32_t)(q * 40 + lane));
    int myidx = (int)((r.a ^ r.b) & 2047u);

    float qv = Q[(((size_t)(b * Lc + q)) * Hc + h) * Dc + lane];
    const float* Kbh = K + ((size_t)b * Lc * Hc + h) * Dc;  // + l*512 + lane
    float mx = -INFINITY, sm = 0.f;
#pragma unroll
    for (int s0 = 0; s0 < 40; s0 += 8) {
        float pv[8];
#pragma unroll
        for (int j = 0; j < 8; ++j) {
            int kk = __builtin_amdgcn_readlane(myidx, s0 + j);  // wave-uniform -> SGPR base
            pv[j] = qv * Kbh[(size_t)kk * 512 + lane];
        }
#pragma unroll
        for (int m = 32; m; m >>= 1)
#pragma unroll
            for (int j = 0; j < 8; ++j) pv[j] += __shfl_xor(pv[j], m, 64);
#pragma unroll
        for (int j = 0; j < 8; ++j) {
            mx = fmaxf(mx, pv[j]);
            sm += pv[j];
        }
    }
    if (lane == 0) M[bh * Lc + q] = mx - sm * (1.0f / 2048.0f);
}

// ---------------- k_topk: register-resident iterative argmax (ties -> smaller idx) --
__global__ __launch_bounds__(256) void k_topk(const float* __restrict__ M, int* __restrict__ top) {
    __shared__ float wvs[4];
    __shared__ int wis[4];
    int bh = blockIdx.x;
    int t = threadIdx.x, lane = t & 63, w = t >> 6;
    float v[8];
#pragma unroll
    for (int i = 0; i < 8; ++i) v[i] = M[bh * Lc + i * 256 + t];
    float bv;
    int bi;
    auto recompute = [&]() {
        bv = v[0];
        bi = t;
#pragma unroll
        for (int i = 1; i < 8; ++i)
            if (v[i] > bv) { bv = v[i]; bi = i * 256 + t; }
    };
    recompute();
    for (int it = 0; it < NUc; ++it) {
        float cv = bv;
        int ci = bi;
#pragma unroll
        for (int m = 1; m < 64; m <<= 1) {
            float ov = __shfl_xor(cv, m, 64);
            int oi = __shfl_xor(ci, m, 64);
            if (ov > cv || (ov == cv && oi < ci)) { cv = ov; ci = oi; }
        }
        if (lane == 0) { wvs[w] = cv; wis[w] = ci; }
        __syncthreads();
        float gv = wvs[0];
        int gi = wis[0];
#pragma unroll
        for (int ww = 1; ww < 4; ++ww) {
            float ov = wvs[ww];
            int oi = wis[ww];
            if (ov > gv || (ov == gv && oi < gi)) { gv = ov; gi = oi; }
        }
        if (t == 0) top[bh * NUc + it] = gi;
        if ((gi & 255) == t) {  // owner removes and rescans its 8
            v[gi >> 8] = -INFINITY;
            recompute();
        }
        __syncthreads();
    }
}

// ---------------- V mean: partial over 256-row chunks, then reduce ---------------
__global__ __launch_bounds__(256) void k_vmean_part(const float* __restrict__ V,
                                                    float* __restrict__ vpart) {
    __shared__ float4 r[256];
    int blk = blockIdx.x;  // bh*8 + chunk
    int chunk = blk & 7, bh = blk >> 3;
    int b = bh >> 3, h = bh & 7;
    int t = threadIdx.x, dq = t & 15, c = t >> 4;  // c in 0..15
    const float4* V4 = reinterpret_cast<const float4*>(V);
    float4 s = make_float4(0.f, 0.f, 0.f, 0.f);
#pragma unroll
    for (int i = 0; i < 16; ++i) {
        int l = chunk * 256 + c + 16 * i;
        float4 p = V4[(size_t)((b * Lc + l) * Hc + h) * 16 + dq];
        s.x += p.x; s.y += p.y; s.z += p.z; s.w += p.w;
    }
    r[t] = s;
    __syncthreads();
    if (t < 16) {
        float4 a = r[t];
#pragma unroll
        for (int g = 1; g < 16; ++g) {
            float4 p = r[t + 16 * g];
            a.x += p.x; a.y += p.y; a.z += p.z; a.w += p.w;
        }
        reinterpret_cast<float4*>(vpart)[blk * 16 + t] = a;
    }
}

__global__ void k_vred(const float* __restrict__ vpart, float* __restrict__ vm) {
    int i = blockIdx.x * 256 + threadIdx.x;  // < 2048 : bh*64 + d
    int bh = i >> 6, d = i & 63;
    float s = 0.f;
#pragma unroll
    for (int c = 0; c < 8; ++c) s += vpart[(bh * 8 + c) * 64 + d];
    vm[i] = s * (1.0f / 2048.0f);
}

// ---------------- attention partials: block = (b,h,chunk of 256 keys) ------------
__global__ __launch_bounds__(256) void k_attn_part(const float* __restrict__ Q,
                                                   const float* __restrict__ K,
                                                   const float* __restrict__ V,
                                                   const int* __restrict__ top,
                                                   float* __restrict__ wsO,
                                                   float* __restrict__ wsm,
                                                   float* __restrict__ wsl) {
    __shared__ float Qs[40][64];        // 10 KB
    __shared__ float pT[4][64][44];     // 44 KB (wave, key-local, u + pad)
    __shared__ float mw[4][40], lw[4][40];
    __shared__ float Mgs[40], Lgs[40];
    __shared__ int tqs[40];
    int blk = blockIdx.x;  // bh*NCH + chunk
    int chunk = blk & (NCH - 1), bh = blk >> 3;
    int b = bh >> 3, h = bh & 7;
    int t = threadIdx.x, w = t >> 6, lane = t & 63;

    if (t < 40) tqs[t] = top[bh * NUc + t];
    __syncthreads();
    for (int i = t; i < 40 * 64; i += 256) {
        int u = i >> 6, d = i & 63;
        Qs[u][d] = Q[(((size_t)(b * Lc + tqs[u])) * Hc + h) * Dc + d];
    }
    __syncthreads();

    // scores: thread t owns key kg = chunk*256 + t; acc[u] = dot(Q[u], K[kg])
    int kg = chunk * CHK + t;
    const float4* Kr = reinterpret_cast<const float4*>(&K[(((size_t)(b * Lc + kg)) * Hc + h) * Dc]);
    float acc[40];
#pragma unroll
    for (int u = 0; u < 40; ++u) acc[u] = 0.f;
#pragma unroll
    for (int i = 0; i < 16; ++i) {
        float4 kv = Kr[i];
#pragma unroll
        for (int u = 0; u < 40; ++u) {
            float4 qv = *reinterpret_cast<const float4*>(&Qs[u][i * 4]);
            acc[u] += qv.x * kv.x + qv.y * kv.y + qv.z * kv.z + qv.w * kv.w;
        }
    }
    // transpose into wave-local LDS (scaled); same-wave, no barrier needed
#pragma unroll
    for (int u = 0; u < 40; ++u) pT[w][lane][u] = acc[u] * 0.125f;
    // wave-local softmax stats over this wave's 64 keys (lane u < 40)
    if (lane < 40) {
        float m = -INFINITY;
        for (int k = 0; k < 64; ++k) m = fmaxf(m, pT[w][k][lane]);
        float s = 0.f;
        for (int k = 0; k < 64; ++k) {
            float e = __expf(pT[w][k][lane] - m);
            pT[w][k][lane] = e;
            s += e;
        }
        mw[w][lane] = m;
        lw[w][lane] = s;
    }
    // PV over this wave's 64 keys: lane = d, acc[u] = sum_k p[u][k] * V[k][d]
#pragma unroll
    for (int u = 0; u < 40; ++u) acc[u] = 0.f;
    const float* Vbh = V + ((size_t)b * Lc * Hc + h) * Dc;
    for (int k = 0; k < 64; ++k) {
        int kk = chunk * CHK + w * 64 + k;
        float vv = Vbh[(size_t)kk * 512 + lane];
#pragma unroll
        for (int u0 = 0; u0 < 40; u0 += 4) {
            float4 p4 = *reinterpret_cast<const float4*>(&pT[w][k][u0]);
            acc[u0] += p4.x * vv;
            acc[u0 + 1] += p4.y * vv;
            acc[u0 + 2] += p4.z * vv;
            acc[u0 + 3] += p4.w * vv;
        }
    }
    __syncthreads();
    // combine 4 waves' stats -> chunk stats; lw becomes per-wave rescale factor
    if (t < 40) {
        float m = fmaxf(fmaxf(mw[0][t], mw[1][t]), fmaxf(mw[2][t], mw[3][t]));
        float L = 0.f;
#pragma unroll
        for (int ww = 0; ww < 4; ++ww) {
            float f = __expf(mw[ww][t] - m);
            L += lw[ww][t] * f;
            lw[ww][t] = f;
        }
        Mgs[t] = m;
        Lgs[t] = L;
    }
    __syncthreads();
    // scale own O by factor, stage into pT region (p no longer needed)
    float* Ow = &pT[w][0][0];
#pragma unroll
    for (int u = 0; u < 40; ++u) Ow[u * 64 + lane] = acc[u] * lw[w][u];
    __syncthreads();
    // sum across waves -> chunk partial (unnormalized, referenced to chunk max)
    const float* o0 = &pT[0][0][0];
    const float* o1 = &pT[1][0][0];
    const float* o2 = &pT[2][0][0];
    const float* o3 = &pT[3][0][0];
    for (int i = t; i < 40 * 64; i += 256)
        wsO[(size_t)blk * 2560 + i] = o0[i] + o1[i] + o2[i] + o3[i];
    if (t < 40) {
        wsm[blk * 40 + t] = Mgs[t];
        wsl[blk * 40 + t] = Lgs[t];
    }
}

// ---------------- combine 8 chunk-partials -> staged rows ------------------------
__global__ __launch_bounds__(256) void k_attn_comb(const float* __restrict__ wsO,
                                                   const float* __restrict__ wsm,
                                                   const float* __restrict__ wsl,
                                                   float* __restrict__ stage) {
    __shared__ float cm[8][40], cl[8][40], cf[8][40];
    int bh = blockIdx.x;
    int t = threadIdx.x;
    // 320 pairs, 256 threads -> strided loop (R2 bug was `if (t < 320)`).
    for (int i = t; i < 8 * 40; i += 256) {
        int c = i / 40, u = i % 40;
        cm[c][u] = wsm[(bh * 8 + c) * 40 + u];
        cl[c][u] = wsl[(bh * 8 + c) * 40 + u];
    }
    __syncthreads();
    if (t < 40) {
        float m = -INFINITY;
#pragma unroll
        for (int c = 0; c < 8; ++c) m = fmaxf(m, cm[c][t]);
        float L = 0.f;
#pragma unroll
        for (int c = 0; c < 8; ++c) {
            float f = __expf(cm[c][t] - m);
            L += cl[c][t] * f;
            cf[c][t] = f;
        }
        float inv = 1.0f / L;
#pragma unroll
        for (int c = 0; c < 8; ++c) cf[c][t] *= inv;
    }
    __syncthreads();
    for (int i = t; i < 2560; i += 256) {
        int u = i >> 6;
        float val = 0.f;
#pragma unroll
        for (int c = 0; c < 8; ++c) val += wsO[((size_t)(bh * 8 + c)) * 2560 + i] * cf[c][u];
        stage[(size_t)bh * 2560 + i] = val;
    }
}

// ---------------- fill with mean(V), then scatter attended rows ------------------
__global__ void k_fill(float* __restrict__ out, const float* __restrict__ vm) {
    int o4 = blockIdx.x * blockDim.x + threadIdx.x;  // over 1M float4
    if (o4 >= Bc * Lc * Hc * (Dc / 4)) return;
    int dq = o4 & 15;
    int h = (o4 >> 4) & 7;
    int bl = o4 >> 7;
    int b = bl >> 11;
    float4 v = reinterpret_cast<const float4*>(vm)[(b * 8 + h) * 16 + dq];
    reinterpret_cast<float4*>(out)[o4] = v;
}

__global__ void k_scatter(const float* __restrict__ stage, const int* __restrict__ top,
                          float* __restrict__ out) {
    int i = blockIdx.x * 256 + threadIdx.x;  // < 32*2560
    if (i >= 32 * 2560) return;
    int bh = i / 2560;
    int rem = i % 2560;
    int u = rem >> 6, d = rem & 63;
    int b = bh >> 3, h = bh & 7;
    int q = top[bh * NUc + u];
    out[(((size_t)(b * Lc + q)) * Hc + h) * Dc + d] = stage[i];
}

extern "C" void kernel_launch(void* const* d_in, const int* in_sizes, int n_in,
                              void* d_out, int out_size, void* d_ws, size_t ws_size,
                              hipStream_t stream) {
    (void)in_sizes; (void)n_in; (void)out_size; (void)ws_size;
    const float* Q = (const float*)d_in[0];
    const float* K = (const float*)d_in[1];
    const float* V = (const float*)d_in[2];
    float* out = (float*)d_out;

    // d_out-as-scratch (16 MB; all consumed before k_fill overwrites it):
    float* wsO = (float*)d_out;                           // 0 .. 2.62 MB
    float* wsm = (float*)((char*)d_out + 3145728);        // 40 KB
    float* wsl = (float*)((char*)d_out + 3276800);        // 40 KB
    float* M   = (float*)((char*)d_out + 4194304);        // 256 KB
    // d_ws (survives past k_fill): ~410 KB total
    int*   top   = (int*)d_ws;                            // 5 KB
    float* stage = (float*)((char*)d_ws + 8192);          // 320 KB
    float* vpart = (float*)((char*)d_ws + 335872);        // 64 KB
    float* vm    = (float*)((char*)d_ws + 401408);        // 8 KB

    hipLaunchKernelGGL(k_M, dim3(Bc * Hc * Lc / 4), dim3(256), 0, stream, Q, K, M);
    hipLaunchKernelGGL(k_topk, dim3(Bc * Hc), dim3(256), 0, stream, M, top);
    hipLaunchKernelGGL(k_vmean_part, dim3(Bc * Hc * 8), dim3(256), 0, stream, V, vpart);
    hipLaunchKernelGGL(k_vred, dim3(8), dim3(256), 0, stream, vpart, vm);
    hipLaunchKernelGGL(k_attn_part, dim3(Bc * Hc * NCH), dim3(256), 0, stream, Q, K, V, top,
                       wsO, wsm, wsl);
    hipLaunchKernelGGL(k_attn_comb, dim3(Bc * Hc), dim3(256), 0, stream, wsO, wsm, wsl, stage);
    hipLaunchKernelGGL(k_fill, dim3(4096), dim3(256), 0, stream, out, vm);
    hipLaunchKernelGGL(k_scatter, dim3(320), dim3(256), 0, stream, stage, top, out);
}

// Round 5
// 135.506 us; speedup vs baseline: 5.4837x; 1.9007x over previous
//
#include <hip/hip_runtime.h>
#include <stdint.h>

// ProbSparse attention (Informer): B=4, L=2048, H=8, D=64, factor=5 -> U_part=u=40.
// out = broadcast mean(V) except top-40 rows per (b,h) get softmax(Q K^T/8) V.
// Row selection is bit-exact jax.random.randint(key(42),(2048,40),0,2048)
// under jax_threefry_partitionable=True (verified passing).
//
// R3: k_M fetch-bound (73 MB) -> XCD-affinity remap -> 16.4 MB but only 202->175 us.
// R4 post-mortem: 240 wave-wide shuffles/wave = ~166 us of LDS-pipe time (measured 175).
// R5 fix: quarter-wave float4 dots -> 54 cross-lane ops/wave (4.4x fewer), 10 vector
// gathers instead of 40 scalar.

static constexpr int Bc = 4, Lc = 2048, Hc = 8, Dc = 64, NUc = 40;
static constexpr int NCH = 8, CHK = 256;  // key chunks for attention

struct TF2 { uint32_t a, b; };

__host__ __device__ constexpr uint32_t rotl32c(uint32_t x, int r) {
    return (x << r) | (x >> (32 - r));
}

// Threefry-2x32, 20 rounds (jax._src.prng.threefry2x32), constexpr-foldable.
__host__ __device__ constexpr TF2 tf2x32c(uint32_t k0, uint32_t k1, uint32_t x0, uint32_t x1) {
    uint32_t ks[3] = {k0, k1, k0 ^ k1 ^ 0x1BD11BDAu};
    const int R0[4] = {13, 15, 26, 6};
    const int R1[4] = {17, 29, 16, 24};
    x0 += ks[0];
    x1 += ks[1];
    for (int i = 0; i < 5; ++i) {
        const int* R = (i & 1) ? R1 : R0;
        for (int j = 0; j < 4; ++j) {
            x0 += x1;
            x1 = rotl32c(x1, R[j]);
            x1 ^= x0;
        }
        x0 += ks[(i + 1) % 3];
        x1 += ks[(i + 2) % 3] + (uint32_t)(i + 1);
    }
    return TF2{x0, x1};
}

// ---------------- k_M: sampled sparsity measure --------------------------------
// wave per q-row. Quarter-wave (16-lane) groups each own one sample per iteration:
// lane gl holds dims [4gl..4gl+3] as float4; dot reduce = 4 shuffle stages over 16
// lanes; 4 samples/iteration, 10 iterations. XCD-affinity block remap keeps each
// (b,h) K-panel resident in one XCD's L2.
__global__ __launch_bounds__(256) void k_M(const float* __restrict__ Q,
                                           const float* __restrict__ K,
                                           float* __restrict__ M) {
    constexpr TF2 K2 = tf2x32c(0u, 42u, 0u, 1u);  // second key of split(key(42))
    int lane = threadIdx.x & 63;
    int w = threadIdx.x >> 6;
    int blk = blockIdx.x;            // 16384 blocks
    int xcd = blk & 7;
    int local = blk >> 3;            // 0..2047 within XCD
    int bh = xcd * 4 + (local >> 9); // 4 panels per XCD
    int q = (local & 511) * 4 + w;
    int b = bh >> 3, h = bh & 7;
    // lane s (<40) computes index_sample[q][s]
    TF2 r = tf2x32c(K2.a, K2.b, 0u, (uint32_t)(q * 40 + lane));
    int myidx = (int)((r.a ^ r.b) & 2047u);

    int grp = lane >> 4;  // 0..3 : sample group
    int gl = lane & 15;   // 0..15 : dim fragment
    const float4* Qrow =
        reinterpret_cast<const float4*>(Q + (((size_t)(b * Lc + q)) * Hc + h) * Dc);
    float4 qv = Qrow[gl];
    const float* Kbh = K + ((size_t)b * Lc * Hc + h) * Dc;  // + l*512

    float mx = -INFINITY, sm = 0.f;
#pragma unroll
    for (int i = 0; i < 10; ++i) {
        int kk = __shfl(myidx, i * 4 + grp, 64);  // per-group sample index
        float4 kv = *reinterpret_cast<const float4*>(Kbh + (size_t)kk * 512 + 4 * gl);
        float pv = qv.x * kv.x + qv.y * kv.y + qv.z * kv.z + qv.w * kv.w;
#pragma unroll
        for (int m = 1; m < 16; m <<= 1) pv += __shfl_xor(pv, m, 64);
        mx = fmaxf(mx, pv);
        sm += pv;
    }
    // combine the 4 groups (each has stats over its 10 samples)
#pragma unroll
    for (int m = 16; m < 64; m <<= 1) {
        mx = fmaxf(mx, __shfl_xor(mx, m, 64));
        sm += __shfl_xor(sm, m, 64);
    }
    if (lane == 0) M[bh * Lc + q] = mx - sm * (1.0f / 2048.0f);
}

// ---------------- k_topk: register-resident iterative argmax (ties -> smaller idx) --
__global__ __launch_bounds__(256) void k_topk(const float* __restrict__ M, int* __restrict__ top) {
    __shared__ float wvs[4];
    __shared__ int wis[4];
    int bh = blockIdx.x;
    int t = threadIdx.x, lane = t & 63, w = t >> 6;
    float v[8];
#pragma unroll
    for (int i = 0; i < 8; ++i) v[i] = M[bh * Lc + i * 256 + t];
    float bv;
    int bi;
    auto recompute = [&]() {
        bv = v[0];
        bi = t;
#pragma unroll
        for (int i = 1; i < 8; ++i)
            if (v[i] > bv) { bv = v[i]; bi = i * 256 + t; }
    };
    recompute();
    for (int it = 0; it < NUc; ++it) {
        float cv = bv;
        int ci = bi;
#pragma unroll
        for (int m = 1; m < 64; m <<= 1) {
            float ov = __shfl_xor(cv, m, 64);
            int oi = __shfl_xor(ci, m, 64);
            if (ov > cv || (ov == cv && oi < ci)) { cv = ov; ci = oi; }
        }
        if (lane == 0) { wvs[w] = cv; wis[w] = ci; }
        __syncthreads();
        float gv = wvs[0];
        int gi = wis[0];
#pragma unroll
        for (int ww = 1; ww < 4; ++ww) {
            float ov = wvs[ww];
            int oi = wis[ww];
            if (ov > gv || (ov == gv && oi < gi)) { gv = ov; gi = oi; }
        }
        if (t == 0) top[bh * NUc + it] = gi;
        if ((gi & 255) == t) {  // owner removes and rescans its 8
            v[gi >> 8] = -INFINITY;
            recompute();
        }
        __syncthreads();
    }
}

// ---------------- V mean: partial over 256-row chunks, then reduce ---------------
__global__ __launch_bounds__(256) void k_vmean_part(const float* __restrict__ V,
                                                    float* __restrict__ vpart) {
    __shared__ float4 r[256];
    int blk = blockIdx.x;  // bh*8 + chunk
    int chunk = blk & 7, bh = blk >> 3;
    int b = bh >> 3, h = bh & 7;
    int t = threadIdx.x, dq = t & 15, c = t >> 4;  // c in 0..15
    const float4* V4 = reinterpret_cast<const float4*>(V);
    float4 s = make_float4(0.f, 0.f, 0.f, 0.f);
#pragma unroll
    for (int i = 0; i < 16; ++i) {
        int l = chunk * 256 + c + 16 * i;
        float4 p = V4[(size_t)((b * Lc + l) * Hc + h) * 16 + dq];
        s.x += p.x; s.y += p.y; s.z += p.z; s.w += p.w;
    }
    r[t] = s;
    __syncthreads();
    if (t < 16) {
        float4 a = r[t];
#pragma unroll
        for (int g = 1; g < 16; ++g) {
            float4 p = r[t + 16 * g];
            a.x += p.x; a.y += p.y; a.z += p.z; a.w += p.w;
        }
        reinterpret_cast<float4*>(vpart)[blk * 16 + t] = a;
    }
}

__global__ void k_vred(const float* __restrict__ vpart, float* __restrict__ vm) {
    int i = blockIdx.x * 256 + threadIdx.x;  // < 2048 : bh*64 + d
    int bh = i >> 6, d = i & 63;
    float s = 0.f;
#pragma unroll
    for (int c = 0; c < 8; ++c) s += vpart[(bh * 8 + c) * 64 + d];
    vm[i] = s * (1.0f / 2048.0f);
}

// ---------------- attention partials: block = (b,h,chunk of 256 keys) ------------
__global__ __launch_bounds__(256) void k_attn_part(const float* __restrict__ Q,
                                                   const float* __restrict__ K,
                                                   const float* __restrict__ V,
                                                   const int* __restrict__ top,
                                                   float* __restrict__ wsO,
                                                   float* __restrict__ wsm,
                                                   float* __restrict__ wsl) {
    __shared__ float Qs[40][64];        // 10 KB
    __shared__ float pT[4][64][44];     // 44 KB (wave, key-local, u + pad)
    __shared__ float mw[4][40], lw[4][40];
    __shared__ float Mgs[40], Lgs[40];
    __shared__ int tqs[40];
    int blk = blockIdx.x;  // bh*NCH + chunk
    int chunk = blk & (NCH - 1), bh = blk >> 3;
    int b = bh >> 3, h = bh & 7;
    int t = threadIdx.x, w = t >> 6, lane = t & 63;

    if (t < 40) tqs[t] = top[bh * NUc + t];
    __syncthreads();
    for (int i = t; i < 40 * 64; i += 256) {
        int u = i >> 6, d = i & 63;
        Qs[u][d] = Q[(((size_t)(b * Lc + tqs[u])) * Hc + h) * Dc + d];
    }
    __syncthreads();

    // scores: thread t owns key kg = chunk*256 + t; acc[u] = dot(Q[u], K[kg])
    int kg = chunk * CHK + t;
    const float4* Kr = reinterpret_cast<const float4*>(&K[(((size_t)(b * Lc + kg)) * Hc + h) * Dc]);
    float acc[40];
#pragma unroll
    for (int u = 0; u < 40; ++u) acc[u] = 0.f;
#pragma unroll
    for (int i = 0; i < 16; ++i) {
        float4 kv = Kr[i];
#pragma unroll
        for (int u = 0; u < 40; ++u) {
            float4 qv = *reinterpret_cast<const float4*>(&Qs[u][i * 4]);
            acc[u] += qv.x * kv.x + qv.y * kv.y + qv.z * kv.z + qv.w * kv.w;
        }
    }
    // transpose into wave-local LDS (scaled); same-wave, no barrier needed
#pragma unroll
    for (int u = 0; u < 40; ++u) pT[w][lane][u] = acc[u] * 0.125f;
    // wave-local softmax stats over this wave's 64 keys (lane u < 40)
    if (lane < 40) {
        float m = -INFINITY;
        for (int k = 0; k < 64; ++k) m = fmaxf(m, pT[w][k][lane]);
        float s = 0.f;
        for (int k = 0; k < 64; ++k) {
            float e = __expf(pT[w][k][lane] - m);
            pT[w][k][lane] = e;
            s += e;
        }
        mw[w][lane] = m;
        lw[w][lane] = s;
    }
    // PV over this wave's 64 keys: lane = d, acc[u] = sum_k p[u][k] * V[k][d]
#pragma unroll
    for (int u = 0; u < 40; ++u) acc[u] = 0.f;
    const float* Vbh = V + ((size_t)b * Lc * Hc + h) * Dc;
    for (int k = 0; k < 64; ++k) {
        int kk = chunk * CHK + w * 64 + k;
        float vv = Vbh[(size_t)kk * 512 + lane];
#pragma unroll
        for (int u0 = 0; u0 < 40; u0 += 4) {
            float4 p4 = *reinterpret_cast<const float4*>(&pT[w][k][u0]);
            acc[u0] += p4.x * vv;
            acc[u0 + 1] += p4.y * vv;
            acc[u0 + 2] += p4.z * vv;
            acc[u0 + 3] += p4.w * vv;
        }
    }
    __syncthreads();
    // combine 4 waves' stats -> chunk stats; lw becomes per-wave rescale factor
    if (t < 40) {
        float m = fmaxf(fmaxf(mw[0][t], mw[1][t]), fmaxf(mw[2][t], mw[3][t]));
        float L = 0.f;
#pragma unroll
        for (int ww = 0; ww < 4; ++ww) {
            float f = __expf(mw[ww][t] - m);
            L += lw[ww][t] * f;
            lw[ww][t] = f;
        }
        Mgs[t] = m;
        Lgs[t] = L;
    }
    __syncthreads();
    // scale own O by factor, stage into pT region (p no longer needed)
    float* Ow = &pT[w][0][0];
#pragma unroll
    for (int u = 0; u < 40; ++u) Ow[u * 64 + lane] = acc[u] * lw[w][u];
    __syncthreads();
    // sum across waves -> chunk partial (unnormalized, referenced to chunk max)
    const float* o0 = &pT[0][0][0];
    const float* o1 = &pT[1][0][0];
    const float* o2 = &pT[2][0][0];
    const float* o3 = &pT[3][0][0];
    for (int i = t; i < 40 * 64; i += 256)
        wsO[(size_t)blk * 2560 + i] = o0[i] + o1[i] + o2[i] + o3[i];
    if (t < 40) {
        wsm[blk * 40 + t] = Mgs[t];
        wsl[blk * 40 + t] = Lgs[t];
    }
}

// ---------------- combine 8 chunk-partials -> staged rows ------------------------
__global__ __launch_bounds__(256) void k_attn_comb(const float* __restrict__ wsO,
                                                   const float* __restrict__ wsm,
                                                   const float* __restrict__ wsl,
                                                   float* __restrict__ stage) {
    __shared__ float cm[8][40], cl[8][40], cf[8][40];
    int bh = blockIdx.x;
    int t = threadIdx.x;
    // 320 pairs, 256 threads -> strided loop (R2 bug was `if (t < 320)`).
    for (int i = t; i < 8 * 40; i += 256) {
        int c = i / 40, u = i % 40;
        cm[c][u] = wsm[(bh * 8 + c) * 40 + u];
        cl[c][u] = wsl[(bh * 8 + c) * 40 + u];
    }
    __syncthreads();
    if (t < 40) {
        float m = -INFINITY;
#pragma unroll
        for (int c = 0; c < 8; ++c) m = fmaxf(m, cm[c][t]);
        float L = 0.f;
#pragma unroll
        for (int c = 0; c < 8; ++c) {
            float f = __expf(cm[c][t] - m);
            L += cl[c][t] * f;
            cf[c][t] = f;
        }
        float inv = 1.0f / L;
#pragma unroll
        for (int c = 0; c < 8; ++c) cf[c][t] *= inv;
    }
    __syncthreads();
    for (int i = t; i < 2560; i += 256) {
        int u = i >> 6;
        float val = 0.f;
#pragma unroll
        for (int c = 0; c < 8; ++c) val += wsO[((size_t)(bh * 8 + c)) * 2560 + i] * cf[c][u];
        stage[(size_t)bh * 2560 + i] = val;
    }
}

// ---------------- fill with mean(V), then scatter attended rows ------------------
__global__ void k_fill(float* __restrict__ out, const float* __restrict__ vm) {
    int o4 = blockIdx.x * blockDim.x + threadIdx.x;  // over 1M float4
    if (o4 >= Bc * Lc * Hc * (Dc / 4)) return;
    int dq = o4 & 15;
    int h = (o4 >> 4) & 7;
    int bl = o4 >> 7;
    int b = bl >> 11;
    float4 v = reinterpret_cast<const float4*>(vm)[(b * 8 + h) * 16 + dq];
    reinterpret_cast<float4*>(out)[o4] = v;
}

__global__ void k_scatter(const float* __restrict__ stage, const int* __restrict__ top,
                          float* __restrict__ out) {
    int i = blockIdx.x * 256 + threadIdx.x;  // < 32*2560
    if (i >= 32 * 2560) return;
    int bh = i / 2560;
    int rem = i % 2560;
    int u = rem >> 6, d = rem & 63;
    int b = bh >> 3, h = bh & 7;
    int q = top[bh * NUc + u];
    out[(((size_t)(b * Lc + q)) * Hc + h) * Dc + d] = stage[i];
}

extern "C" void kernel_launch(void* const* d_in, const int* in_sizes, int n_in,
                              void* d_out, int out_size, void* d_ws, size_t ws_size,
                              hipStream_t stream) {
    (void)in_sizes; (void)n_in; (void)out_size; (void)ws_size;
    const float* Q = (const float*)d_in[0];
    const float* K = (const float*)d_in[1];
    const float* V = (const float*)d_in[2];
    float* out = (float*)d_out;

    // d_out-as-scratch (16 MB; all consumed before k_fill overwrites it):
    float* wsO = (float*)d_out;                           // 0 .. 2.62 MB
    float* wsm = (float*)((char*)d_out + 3145728);        // 40 KB
    float* wsl = (float*)((char*)d_out + 3276800);        // 40 KB
    float* M   = (float*)((char*)d_out + 4194304);        // 256 KB
    // d_ws (survives past k_fill): ~410 KB total
    int*   top   = (int*)d_ws;                            // 5 KB
    float* stage = (float*)((char*)d_ws + 8192);          // 320 KB
    float* vpart = (float*)((char*)d_ws + 335872);        // 64 KB
    float* vm    = (float*)((char*)d_ws + 401408);        // 8 KB

    hipLaunchKernelGGL(k_M, dim3(Bc * Hc * Lc / 4), dim3(256), 0, stream, Q, K, M);
    hipLaunchKernelGGL(k_topk, dim3(Bc * Hc), dim3(256), 0, stream, M, top);
    hipLaunchKernelGGL(k_vmean_part, dim3(Bc * Hc * 8), dim3(256), 0, stream, V, vpart);
    hipLaunchKernelGGL(k_vred, dim3(8), dim3(256), 0, stream, vpart, vm);
    hipLaunchKernelGGL(k_attn_part, dim3(Bc * Hc * NCH), dim3(256), 0, stream, Q, K, V, top,
                       wsO, wsm, wsl);
    hipLaunchKernelGGL(k_attn_comb, dim3(Bc * Hc), dim3(256), 0, stream, wsO, wsm, wsl, stage);
    hipLaunchKernelGGL(k_fill, dim3(4096), dim3(256), 0, stream, out, vm);
    hipLaunchKernelGGL(k_scatter, dim3(320), dim3(256), 0, stream, stage, top, out);
}